// Round 9
// baseline (101.260 us; speedup 1.0000x reference)
//
#include <hip/hip_runtime.h>

// AugmentShallow, round 9: round-7 math (proven absmax 9.77e-4), re-tiled
// for deep per-block pipelines.
//
// Diagnosis of the stubborn ~50us kernels: all pipes idle (Mfma 6%, VALU 14%,
// HBM <20%, Occ 18%) across every small-tile variant -> latency-bound from
// SHALLOW per-block phases (32-128 pts, ~24 loads, barrier, short GEMM).
// Fix: 512-thread blocks, 128 pts/block, 512 blocks, 2 blocks/CU co-resident
// (k_mlp 64KiB LDS, k_out 32KiB). Weight fragments amortize over 4 p-tiles;
// gather issues 48 independent loads per thread-quad before any use.
//
// Pipeline: k_prep (row-major f16 hi/lo planes — round-7 verbatim) ;
//           k_mlp (t = MLP(x), f16) ; k_out (gather-mean -> LDS -> W2 GEMM).
// ws: [0,16Mi) t f16 [65536][128]; [16Mi,+256Ki) planes.

typedef __attribute__((ext_vector_type(8))) _Float16 h8;
typedef __attribute__((ext_vector_type(4))) _Float16 h4;
typedef __attribute__((ext_vector_type(4))) float    f4;

#define MFMA_H __builtin_amdgcn_mfma_f32_16x16x32_f16

#define LO_SCALE_INV 2.44140625e-4f   // 2^-12

// plane offsets in f16 elements
#define WC0H 0
#define WC0L 16384
#define WC1H 32768
#define WC1L 49152
#define W2H  65536
#define W2L  98304

// ---------------------------------------------------------------------------
// Prep (round-7 verbatim): split Wc0/Wc1/W2 into f16 hi/lo planes.
// ---------------------------------------------------------------------------
__global__ void k_prep(const float* __restrict__ Wc0, const float* __restrict__ Wc1,
                       const float* __restrict__ W2, _Float16* __restrict__ planes)
{
    const int i = blockIdx.x * 256 + threadIdx.x;   // 0..65535
    float v; _Float16 *ph, *pl;
    if (i < 16384) {
        v = Wc0[i]; ph = planes + WC0H + i; pl = planes + WC0L + i;
    } else if (i < 32768) {
        const int j = i - 16384;
        v = Wc1[j]; ph = planes + WC1H + j; pl = planes + WC1L + j;
    } else {
        const int j = i - 32768;
        v = W2[j];  ph = planes + W2H + j;  pl = planes + W2L + j;
    }
    const _Float16 h = (_Float16)v;
    *ph = h;
    *pl = (_Float16)((v - (float)h) * 4096.f);
}

// One 32-oc x 64-pt GEMM pass (4 p-tiles at rows phbase + p*16 + fr).
template <class F>
__device__ __forceinline__ void pass32b(
    const _Float16* __restrict__ hin,     // LDS [128][128], chunk^p7 swizzle
    const _Float16* __restrict__ wh,
    const _Float16* __restrict__ wl,
    const float* __restrict__ bias,       // may be nullptr
    int phbase, int fr, int g, F&& emit)
{
    h8 Ah[2][4], Al[2][4];
#pragma unroll
    for (int T = 0; T < 2; ++T)
#pragma unroll
        for (int c = 0; c < 4; ++c) {
            const long off = (long)(T * 16 + fr) * 128 + c * 32 + g * 8;
            Ah[T][c] = *(const h8*)(wh + off);
            Al[T][c] = *(const h8*)(wl + off);
        }

    f4 bv[2] = {{0.f, 0.f, 0.f, 0.f}, {0.f, 0.f, 0.f, 0.f}};
    if (bias) {
#pragma unroll
        for (int T = 0; T < 2; ++T) {
            const float4 q = *(const float4*)(bias + T * 16 + g * 4);
            bv[T] = (f4){q.x, q.y, q.z, q.w};
        }
    }

#pragma unroll
    for (int p = 0; p < 4; ++p) {
        const int pt = phbase + p * 16 + fr;
        const int p7 = pt & 7;
        h8 B[4];
#pragma unroll
        for (int c = 0; c < 4; ++c)
            B[c] = *(const h8*)&hin[pt * 128 + (((4 * c + g) ^ p7) << 3)];

        f4 ahi[2] = {bv[0], bv[1]};
        f4 alo[2] = {{0.f, 0.f, 0.f, 0.f}, {0.f, 0.f, 0.f, 0.f}};
#pragma unroll
        for (int c = 0; c < 4; ++c)
#pragma unroll
            for (int T = 0; T < 2; ++T) {
                ahi[T] = MFMA_H(Ah[T][c], B[c], ahi[T], 0, 0, 0);
                alo[T] = MFMA_H(Al[T][c], B[c], alo[T], 0, 0, 0);
            }
        f4 rv[2];
#pragma unroll
        for (int T = 0; T < 2; ++T)
#pragma unroll
            for (int j = 0; j < 4; ++j)
                rv[T][j] = fmaf(alo[T][j], LO_SCALE_INV, ahi[T][j]);
        emit(p, rv);
    }
}

// ---------------------------------------------------------------------------
// Kernel 1: point MLP. 512 blocks x 512 thr, 128 points per block.
// Waves: w = (ph = w&1, st = w>>1); wave handles 64-pt half x 32-oc strip.
// ---------------------------------------------------------------------------
__global__ __launch_bounds__(512) void k_mlp(
    const float* __restrict__ x,
    const float* __restrict__ W1, const float* __restrict__ b1,
    const float* __restrict__ bc0, const float* __restrict__ bc1,
    const _Float16* __restrict__ planes,
    _Float16* __restrict__ t)
{
    __shared__ __align__(16) _Float16 hA[128 * 128];   // 32 KiB
    __shared__ __align__(16) _Float16 hB[128 * 128];   // 32 KiB

    const int tid = threadIdx.x;
    const int bid = blockIdx.x;
    const int lb  = (bid & 7) * 64 + (bid >> 3);    // batch = lb>>6 = bid&7
    const long pblk = (long)lb * 128;

    // ---- layer 1 (VALU, K=3, no relu): thread = (pt, 32-ch quarter) ----
    {
        const int pt  = tid >> 2;                    // 0..127
        const int q4  = tid & 3;
        const int ch0 = q4 * 32;
        const float* xp = x + (pblk + pt) * 3;
        const float x0 = xp[0], x1 = xp[1], x2 = xp[2];
        const int p7 = pt & 7;
#pragma unroll
        for (int q = 0; q < 4; ++q) {
            h8 hv;
#pragma unroll
            for (int j = 0; j < 8; ++j) {
                const int c = ch0 + q * 8 + j;
                float v = b1[c];
                v = fmaf(W1[c * 3 + 0], x0, v);
                v = fmaf(W1[c * 3 + 1], x1, v);
                v = fmaf(W1[c * 3 + 2], x2, v);
                hv[j] = (_Float16)v;
            }
            const int chunk = q4 * 4 + q;
            *(h8*)&hA[pt * 128 + ((chunk ^ p7) << 3)] = hv;
        }
    }
    __syncthreads();

    const int lane = tid & 63;
    const int w   = tid >> 6;        // 0..7
    const int ph  = (w & 1) * 64;    // pt-half base
    const int st  = w >> 1;          // 0..3 oc strip
    const int fr  = lane & 15;
    const int g   = lane >> 4;
    const int ocb = st * 32;
    const long strip = (long)ocb * 128;

    auto storeMid = [&](_Float16* hout, int p, f4* rv) {
        const int pt = ph + p * 16 + fr;
        const int p7 = pt & 7;
#pragma unroll
        for (int T = 0; T < 2; ++T) {
            const int ocoff = ocb + T * 16 + g * 4;
            h4 o;
#pragma unroll
            for (int r = 0; r < 4; ++r) o[r] = (_Float16)fmaxf(rv[T][r], 0.f);
            const int sidx = pt * 128 + (((ocoff >> 3) ^ p7) << 3) + (ocoff & 7);
            *(h4*)&hout[sidx] = o;
        }
    };

    // ---- layer 2: hB = relu(Wc0 hA + bc0) ----
    pass32b(hA, planes + WC0H + strip, planes + WC0L + strip, bc0 + ocb, ph, fr, g,
            [&](int p, f4* rv) { storeMid(hB, p, rv); });
    __syncthreads();

    // ---- layer 3: t = relu(Wc1 hB + bc1), direct to global ----
    pass32b(hB, planes + WC1H + strip, planes + WC1L + strip, bc1 + ocb, ph, fr, g,
            [&](int p, f4* rv) {
                const int ptl = ph + p * 16 + fr;
                const long pt = pblk + ptl;
#pragma unroll
                for (int T = 0; T < 2; ++T) {
                    const int ocoff = ocb + T * 16 + g * 4;
                    h4 o;
#pragma unroll
                    for (int r = 0; r < 4; ++r)
                        o[r] = (_Float16)fmaxf(rv[T][r], 0.f);
                    *(h4*)&t[pt * 128 + ocoff] = o;
                }
            });
}

// ---------------------------------------------------------------------------
// Kernel 2: gather-mean -> LDS -> out = W2 m + b2. 512 blocks x 512 thr,
// 128 pts per block (bid&7 -> XCD pin). Gather: thread = (pt, 32-ch quarter),
// 48 independent 16B loads. GEMM: waves (ph, st), 2 oc-halves each.
// ---------------------------------------------------------------------------
__global__ __launch_bounds__(512) void k_out(
    const int* __restrict__ knn,
    const _Float16* __restrict__ t,
    const _Float16* __restrict__ planes,
    const float* __restrict__ b2,
    float* __restrict__ out)
{
    __shared__ __align__(16) _Float16 mS[128 * 128];   // 32 KiB

    const int tid = threadIdx.x;
    const int bid = blockIdx.x;
    const int lb  = (bid & 7) * 64 + (bid >> 3);    // batch = lb>>6 = bid&7
    const long pbase = (long)lb * 128;
    const long bbase = (long)(bid & 7) * 8192;      // batch row base in t

    const int lane = tid & 63;
    const int w   = tid >> 6;
    const int ph  = (w & 1) * 64;
    const int st  = w >> 1;
    const int fr  = lane & 15;
    const int g   = lane >> 4;

    auto loadW = [&](int ocb, h8 (&Ah)[2][4], h8 (&Al)[2][4]) {
#pragma unroll
        for (int T = 0; T < 2; ++T)
#pragma unroll
            for (int c = 0; c < 4; ++c) {
                const long off = (long)(ocb + T * 16 + fr) * 128 + c * 32 + g * 8;
                Ah[T][c] = *(const h8*)(planes + W2H + off);
                Al[T][c] = *(const h8*)(planes + W2L + off);
            }
    };

    // issue W2 half-0 fragment loads first; latency hides under the gather
    h8 Ah[2][4], Al[2][4];
    loadW(0 + st * 32, Ah, Al);

    // ---- gather-mean into LDS: thread = (pt, 32-ch quarter) ----
    {
        const int pt  = tid >> 2;                    // 0..127
        const int q4  = tid & 3;
        const int o32 = q4 * 32;                     // f16 offset in row
        const int* ip = knn + (pbase + pt) * 12;
        int idx[12];
        *(int4*)&idx[0] = *(const int4*)(ip + 0);
        *(int4*)&idx[4] = *(const int4*)(ip + 4);
        *(int4*)&idx[8] = *(const int4*)(ip + 8);

        float acc[32];
#pragma unroll
        for (int c = 0; c < 32; ++c) acc[c] = 0.f;
#pragma unroll
        for (int k = 0; k < 12; ++k) {
            const _Float16* tp = t + (bbase + idx[k]) * 128 + o32;
#pragma unroll
            for (int q = 0; q < 4; ++q) {
                const h8 v = *(const h8*)(tp + q * 8);
#pragma unroll
                for (int j = 0; j < 8; ++j) acc[q * 8 + j] += (float)v[j];
            }
        }
        const int p7 = pt & 7;
#pragma unroll
        for (int q = 0; q < 4; ++q) {
            h8 o;
#pragma unroll
            for (int j = 0; j < 8; ++j)
                o[j] = (_Float16)(acc[q * 8 + j] * (1.f / 12.f));
            const int chunk = q4 * 4 + q;
            *(h8*)&mS[pt * 128 + ((chunk ^ p7) << 3)] = o;
        }
    }
    __syncthreads();

    // ---- GEMM: out = W2 m + b2, two 128-oc halves per wave ----
#pragma unroll 1
    for (int half = 0; half < 2; ++half) {
        const int ocb = half * 128 + st * 32;
        if (half) loadW(ocb, Ah, Al);

        f4 bv[2];
#pragma unroll
        for (int T = 0; T < 2; ++T) {
            const float4 q = *(const float4*)(b2 + ocb + T * 16 + g * 4);
            bv[T] = (f4){q.x, q.y, q.z, q.w};
        }

#pragma unroll
        for (int p = 0; p < 4; ++p) {
            const int ptl = ph + p * 16 + fr;
            const int p7  = ptl & 7;
            h8 B[4];
#pragma unroll
            for (int c = 0; c < 4; ++c)
                B[c] = *(const h8*)&mS[ptl * 128 + (((4 * c + g) ^ p7) << 3)];

            f4 ahi[2] = {bv[0], bv[1]};
            f4 alo[2] = {{0.f, 0.f, 0.f, 0.f}, {0.f, 0.f, 0.f, 0.f}};
#pragma unroll
            for (int c = 0; c < 4; ++c)
#pragma unroll
                for (int T = 0; T < 2; ++T) {
                    ahi[T] = MFMA_H(Ah[T][c], B[c], ahi[T], 0, 0, 0);
                    alo[T] = MFMA_H(Al[T][c], B[c], alo[T], 0, 0, 0);
                }
#pragma unroll
            for (int T = 0; T < 2; ++T) {
                float4 o;
                o.x = fmaf(alo[T][0], LO_SCALE_INV, ahi[T][0]);
                o.y = fmaf(alo[T][1], LO_SCALE_INV, ahi[T][1]);
                o.z = fmaf(alo[T][2], LO_SCALE_INV, ahi[T][2]);
                o.w = fmaf(alo[T][3], LO_SCALE_INV, ahi[T][3]);
                *(float4*)&out[(pbase + ptl) * 256 + ocb + T * 16 + g * 4] = o;
            }
        }
    }
}

// ---------------------------------------------------------------------------

extern "C" void kernel_launch(void* const* d_in, const int* in_sizes, int n_in,
                              void* d_out, int out_size, void* d_ws, size_t ws_size,
                              hipStream_t stream)
{
    const float* x   = (const float*)d_in[0];
    const int*   knn = (const int*)d_in[1];
    const float* W1  = (const float*)d_in[2];
    const float* b1  = (const float*)d_in[3];
    const float* Wc0 = (const float*)d_in[4];
    const float* bc0 = (const float*)d_in[5];
    const float* Wc1 = (const float*)d_in[6];
    const float* bc1 = (const float*)d_in[7];
    const float* W2  = (const float*)d_in[8];
    const float* b2  = (const float*)d_in[9];
    float* out = (float*)d_out;

    _Float16* t      = (_Float16*)d_ws;                                      // 16 MiB
    _Float16* planes = (_Float16*)((char*)d_ws + (size_t)16 * 1024 * 1024);  // 256 KiB

    k_prep<<<dim3(256), dim3(256), 0, stream>>>(Wc0, Wc1, W2, planes);
    k_mlp <<<dim3(512), dim3(512), 0, stream>>>(x, W1, b1, bc0, bc1, planes, t);
    k_out <<<dim3(512), dim3(512), 0, stream>>>(knn, t, planes, b2, out);
}